// Round 4
// baseline (75.641 us; speedup 1.0000x reference)
//
#include <hip/hip_runtime.h>
#include <math.h>

// ---- problem constants ----
#define DG   32
#define UF   4
#define ZB   16
#define FD   16
#define HH   128
#define WWID 128
#define SNUM 128
#define BATCH 2
#define RAYS  8192
#define NTOK  2048
#define DINP  512
#define ODIM  4096
#define MLPH  32

// d_out float offsets: (pred_depths, weights, nfg)
#define OUT_PRED_OFF 0
#define OUT_W_OFF    (BATCH*RAYS)
#define OUT_NFG_OFF  (OUT_W_OFF + BATCH*RAYS*SNUM)

typedef _Float16 half8 __attribute__((ext_vector_type(8)));
typedef _Float16 half4 __attribute__((ext_vector_type(4)));
typedef _Float16 h2 __attribute__((ext_vector_type(2)));
typedef float f32x4 __attribute__((ext_vector_type(4)));

#define GLDS16(gp, lp) \
    __builtin_amdgcn_global_load_lds((const __attribute__((address_space(1))) void*)(gp), \
                                     (__attribute__((address_space(3))) void*)(lp), 16, 0, 0)

// ---------------- merged prep: blocks [0,NTOK) = LayerNorm, [NTOK,NTOK+512) = W1 transpose ----------------
__global__ __launch_bounds__(256) void prep_kernel(const float* __restrict__ dec,
                                                   const float* __restrict__ lng,
                                                   const float* __restrict__ lnb,
                                                   const float* __restrict__ W2,
                                                   const float* __restrict__ b2,
                                                   const float* __restrict__ W3,
                                                   const float* __restrict__ W1,
                                                   _Float16* __restrict__ Af,
                                                   _Float16* __restrict__ W1T,
                                                   _Float16* __restrict__ W2f,
                                                   float* __restrict__ b2f,
                                                   float* __restrict__ w3f) {
    int tid = threadIdx.x;
    if (blockIdx.x < NTOK) {
        // ---- LayerNorm -> f16 A (block 0 also packs MLP frags) ----
        int t = blockIdx.x;
        const float2* row = reinterpret_cast<const float2*>(dec + (size_t)t * DINP);
        float2 v = row[tid];

        __shared__ float red[4];
        __shared__ float stat[2];

        float s = v.x + v.y;
        #pragma unroll
        for (int o = 32; o > 0; o >>= 1) s += __shfl_down(s, o);
        if ((tid & 63) == 0) red[tid >> 6] = s;
        __syncthreads();
        if (tid == 0) stat[0] = (red[0] + red[1] + red[2] + red[3]) * (1.0f / DINP);
        __syncthreads();
        float mu = stat[0];

        float dx = v.x - mu, dy = v.y - mu;
        float q = dx * dx + dy * dy;
        #pragma unroll
        for (int o = 32; o > 0; o >>= 1) q += __shfl_down(q, o);
        if ((tid & 63) == 0) red[tid >> 6] = q;
        __syncthreads();
        if (tid == 0) {
            float var = (red[0] + red[1] + red[2] + red[3]) * (1.0f / DINP);
            stat[1] = 1.0f / sqrtf(var + 1e-5f);
        }
        __syncthreads();
        float rstd = stat[1];

        int c = 2 * tid;
        h2 o2;
        o2.x = (_Float16)(dx * rstd * lng[c]     + lnb[c]);
        o2.y = (_Float16)(dy * rstd * lng[c + 1] + lnb[c + 1]);
        *reinterpret_cast<h2*>(Af + (size_t)t * DINP + c) = o2;

        // block 0: pack MLP weights into MFMA fragment order.
        if (blockIdx.x == 0 && tid < 128) {
            int jt = tid >> 6, l = tid & 63;
            int sub = l & 15, g = l >> 4;
            #pragma unroll
            for (int e = 0; e < 4; ++e) {
                W2f[(jt * 64 + l) * 4 + e] = (_Float16)W2[(g * 4 + e) * MLPH + jt * 16 + sub];
                b2f[(jt * 64 + l) * 4 + e] = b2[jt * 16 + g * 4 + e];
                w3f[(jt * 64 + l) * 4 + e] = W3[jt * 16 + g * 4 + e];
            }
        }
    } else {
        // ---- W1 (512x4096 f32) -> W1T (4096x512 f16) ----
        __shared__ float st[64][65];
        int blk = blockIdx.x - NTOK;          // [0, 512)
        int c0 = (blk & 63) * 64;
        int k0 = (blk >> 6) * 64;
        {
            int r = tid >> 2, cq = (tid & 3) * 16;
            const float* src = W1 + (size_t)(k0 + r) * ODIM + c0 + cq;
            #pragma unroll
            for (int qq = 0; qq < 4; ++qq) {
                float4 v = *reinterpret_cast<const float4*>(src + qq * 4);
                st[r][cq + qq * 4 + 0] = v.x;
                st[r][cq + qq * 4 + 1] = v.y;
                st[r][cq + qq * 4 + 2] = v.z;
                st[r][cq + qq * 4 + 3] = v.w;
            }
        }
        __syncthreads();
        {
            int cc = tid >> 2, kq = (tid & 3) * 16;
            _Float16 tmp[16];
            #pragma unroll
            for (int i = 0; i < 16; ++i) tmp[i] = (_Float16)st[kq + i][cc];
            _Float16* dst = W1T + (size_t)(c0 + cc) * DINP + k0 + kq;
            *reinterpret_cast<half8*>(dst)     = *reinterpret_cast<half8*>(&tmp[0]);
            *reinterpret_cast<half8*>(dst + 8) = *reinterpret_cast<half8*>(&tmp[8]);
        }
    }
}

// ---------------- MFMA GEMM -> grid_h (B,Z,H,W,F) f16 ----------------
__global__ __launch_bounds__(256, 2) void gemm_mfma_kernel(
        const _Float16* __restrict__ Af, const _Float16* __restrict__ W1T,
        const float* __restrict__ bias, _Float16* __restrict__ gh) {
    __shared__ _Float16 As[128 * 32];
    __shared__ _Float16 Bs[128 * 32];

    int tid = threadIdx.x;
    int l = tid & 63, w = tid >> 6;
    int wr = w >> 1, wc = w & 1;
    int row0 = blockIdx.y * 128;
    int col0 = blockIdx.x * 128;

    const char* Ag0 = (const char*)Af + (size_t)(row0 + w * 32 + (l >> 2)) * (DINP * 2) + (l & 3) * 16;
    const char* Ag1 = Ag0 + 16 * (DINP * 2);
    const char* Bg0 = (const char*)W1T + (size_t)(col0 + w * 32 + (l >> 2)) * (DINP * 2) + (l & 3) * 16;
    const char* Bg1 = Bg0 + 16 * (DINP * 2);
    char* lA0 = (char*)As + w * 2048;
    char* lA1 = lA0 + 1024;
    char* lB0 = (char*)Bs + w * 2048;
    char* lB1 = lB0 + 1024;

    f32x4 acc[4][4] = {};

    for (int kk = 0; kk < DINP; kk += 32) {
        GLDS16(Ag0, lA0); GLDS16(Ag1, lA1);
        GLDS16(Bg0, lB0); GLDS16(Bg1, lB1);
        Ag0 += 64; Ag1 += 64; Bg0 += 64; Bg1 += 64;
        __syncthreads();

        half8 af[4], bf[4];
        #pragma unroll
        for (int m = 0; m < 4; ++m)
            af[m] = *reinterpret_cast<const half8*>(As + (wr * 64 + m * 16 + (l & 15)) * 32 + (l >> 4) * 8);
        #pragma unroll
        for (int n = 0; n < 4; ++n)
            bf[n] = *reinterpret_cast<const half8*>(Bs + (wc * 64 + n * 16 + (l & 15)) * 32 + (l >> 4) * 8);
        #pragma unroll
        for (int m = 0; m < 4; ++m)
            #pragma unroll
            for (int n = 0; n < 4; ++n)
                acc[m][n] = __builtin_amdgcn_mfma_f32_16x16x32_f16(af[m], bf[n], acc[m][n], 0, 0, 0);
        __syncthreads();
    }

    #pragma unroll
    for (int n = 0; n < 4; ++n) {
        int c = col0 + wc * 64 + n * 16 + (l & 15);
        float bv = bias[c];
        int f = c & 15, z = (c >> 4) & 15, v = (c >> 8) & 3, u = (c >> 10) & 3;
        #pragma unroll
        for (int m = 0; m < 4; ++m) {
            int rbase = row0 + wr * 64 + m * 16 + ((l >> 4) << 2);
            #pragma unroll
            for (int j = 0; j < 4; ++j) {
                int t = rbase + j;
                int bb = t >> 10;
                int g = t & 1023;
                int i = g >> 5, j2 = g & 31;
                int h = i * 4 + u, wq = j2 * 4 + v;
                size_t gaddr = ((((size_t)(bb * ZB + z) * HH + h) * WWID + wq) << 4) + f;
                gh[gaddr] = (_Float16)(acc[m][n][j] + bv);
            }
        }
    }
}

// ---------------- transpose grid_h (B,Z,H,W,F) f16 -> nfg (B,F,Z,H,W) f32 ----------------
__global__ __launch_bounds__(256) void tp_kernel(const _Float16* __restrict__ gh,
                                                 float* __restrict__ nfg) {
    int blk = blockIdx.x;           // b*2048 + z*128 + h
    int bb = blk >> 11, z = (blk >> 7) & 15, h = blk & 127;
    __shared__ float sl[128 * 17];  // [w][f] padded
    int tid = threadIdx.x;
    const uint4* src = reinterpret_cast<const uint4*>(gh + (size_t)blk * 2048);
    uint4 v = src[tid];             // 8 f16; idx = tid*8
    int wv = tid >> 1, fb = (tid & 1) * 8;
    h2 p0 = __builtin_bit_cast(h2, v.x);
    h2 p1 = __builtin_bit_cast(h2, v.y);
    h2 p2 = __builtin_bit_cast(h2, v.z);
    h2 p3 = __builtin_bit_cast(h2, v.w);
    float* sr = &sl[wv * 17 + fb];
    sr[0] = (float)p0.x; sr[1] = (float)p0.y;
    sr[2] = (float)p1.x; sr[3] = (float)p1.y;
    sr[4] = (float)p2.x; sr[5] = (float)p2.y;
    sr[6] = (float)p3.x; sr[7] = (float)p3.y;
    __syncthreads();
    int f = tid >> 4, w0 = (tid & 15) * 8;
    float* dst = nfg + (((size_t)(bb * FD + f) * ZB + z) * (HH * WWID)) + h * WWID + w0;
    float4 o0, o1;
    o0.x = sl[(w0 + 0) * 17 + f]; o0.y = sl[(w0 + 1) * 17 + f];
    o0.z = sl[(w0 + 2) * 17 + f]; o0.w = sl[(w0 + 3) * 17 + f];
    o1.x = sl[(w0 + 4) * 17 + f]; o1.y = sl[(w0 + 5) * 17 + f];
    o1.z = sl[(w0 + 6) * 17 + f]; o1.w = sl[(w0 + 7) * 17 + f];
    *reinterpret_cast<float4*>(dst) = o0;
    *reinterpret_cast<float4*>(dst + 4) = o1;
}

// ---------------- ray kernel v3: chunk-across-lanes gather ----------------
// Per round, 16 samples; a 4-lane quad serves one sample; lane c=lane&3 loads
// 16B chunk c of the sample's 64B (w0,w0+1) pair for each of the 4 (d,h) corner
// lines. One VMEM instruction covers 16 samples' FULL pairs -> no per-chunk
// cache-line re-touch in the TA (the old layout paid each line 4x, once per
// 16B chunk instruction). Per-sample corner math computed once per lane up
// front (lane <-> samples lane, lane+64) and broadcast to quads via shfl.
#define SF 24   // feat LDS stride (halves)

struct RayCtx {
    int   off[2][4];   // per sample-set, 4 (d,h) pair base offsets (elements)
    float wdh[2][4];   // per-pair (ad*ah) weights
    float ws[2][2];    // w-side weights ws0, ws1
    int   lv[2];       // live flags
};

template <int R>
__device__ __forceinline__ void rissue(const _Float16* __restrict__ gb,
                                       int sq, int cch, int side,
                                       const RayCtx& C,
                                       uint4 (&L)[4], float (&u)[4], int& lv) {
    constexpr int st = (R < 4) ? 0 : 1;
    const int srcl = ((R % 4) * 16) + sq;       // source lane holding this sample's ctx
    int o[4]; float wd[4];
    #pragma unroll
    for (int p = 0; p < 4; ++p) {
        o[p]  = __shfl(C.off[st][p], srcl);
        wd[p] = __shfl(C.wdh[st][p], srcl);
    }
    float wsa = __shfl(C.ws[st][0], srcl);
    float wsb = __shfl(C.ws[st][1], srcl);
    float wss = side ? wsb : wsa;
    lv = __shfl(C.lv[st], srcl);
    #pragma unroll
    for (int p = 0; p < 4; ++p) u[p] = wd[p] * wss;
    if (lv) {
        #pragma unroll
        for (int p = 0; p < 4; ++p)
            L[p] = *reinterpret_cast<const uint4*>(gb + o[p] + cch * 8);
    }
}

__device__ __forceinline__ void rconsume(_Float16* __restrict__ FL,
                                         int row, int cch, int side,
                                         const uint4 (&L)[4], const float (&u)[4],
                                         int lv) {
    h2 a0 = {}, a1 = {}, a2 = {}, a3 = {};
    if (lv) {
        #pragma unroll
        for (int p = 0; p < 4; ++p) {
            _Float16 uh = (_Float16)u[p];
            h2 U = {uh, uh};
            a0 += __builtin_bit_cast(h2, L[p].x) * U;
            a1 += __builtin_bit_cast(h2, L[p].y) * U;
            a2 += __builtin_bit_cast(h2, L[p].z) * U;
            a3 += __builtin_bit_cast(h2, L[p].w) * U;
        }
    }
    // combine w0-side (lanes c<2) with w1-side (lanes c>=2): partner = lane^2
    a0 += __builtin_bit_cast(h2, __shfl_xor(__builtin_bit_cast(int, a0), 2));
    a1 += __builtin_bit_cast(h2, __shfl_xor(__builtin_bit_cast(int, a1), 2));
    a2 += __builtin_bit_cast(h2, __shfl_xor(__builtin_bit_cast(int, a2), 2));
    a3 += __builtin_bit_cast(h2, __shfl_xor(__builtin_bit_cast(int, a3), 2));
    if (side == 0) {   // lanes c=0 (feat 0-7), c=1 (feat 8-15) write the row
        uint4 o;
        o.x = __builtin_bit_cast(unsigned int, a0);
        o.y = __builtin_bit_cast(unsigned int, a1);
        o.z = __builtin_bit_cast(unsigned int, a2);
        o.w = __builtin_bit_cast(unsigned int, a3);
        *reinterpret_cast<uint4*>(FL + row * SF + (cch & 1) * 8) = o;
    }
}

__global__ __launch_bounds__(256) void ray_fused_kernel(
        const float* __restrict__ orig, const float* __restrict__ dirs,
        const _Float16* __restrict__ gh,
        const _Float16* __restrict__ W2f, const float* __restrict__ b2f,
        const float* __restrict__ w3f, const float* __restrict__ b3,
        float* __restrict__ pred_out, float* __restrict__ w_out) {
    int tid = threadIdx.x;
    int lane = tid & 63, wvid = tid >> 6;
    int ray = blockIdx.x * 4 + wvid;
    int bb = ray >> 13;

    __shared__ _Float16 featLDS[4 * 64 * SF];   // 12KB
    _Float16* FL = &featLDS[wvid * 64 * SF];

    const float* o3 = orig + (size_t)ray * 3;
    const float* d3 = dirs + (size_t)ray * 3;
    float ox = o3[0], oy = o3[1], oz = o3[2];
    float dx = d3[0], dy = d3[1], dz = d3[2];
    const _Float16* gb = gh + (size_t)bb * (ZB * HH * WWID * FD);

    float t0 = 1.0f + 49.0f * ((float)lane * (1.0f / 127.0f));
    float t1 = 1.0f + 49.0f * ((float)(lane + 64) * (1.0f / 127.0f));

    // ---- per-lane corner math for this lane's two samples (lane, lane+64) ----
    RayCtx C;
    #pragma unroll
    for (int ss = 0; ss < 2; ++ss) {
        float t = ss ? t1 : t0;
        float px = ox + dx * t, py = oy + dy * t, pz = oz + dz * t;
        float fw = (py * (1.0f / 51.2f) + 1.0f) * 63.5f;
        float fh = (px * (1.0f / 51.2f) + 1.0f) * 63.5f;
        float fd = (pz + 5.0f) * (0.25f * 7.5f);
        float w0f = floorf(fw), h0f = floorf(fh), d0f = floorf(fd);
        float tw = fw - w0f, th = fh - h0f, td = fd - d0f;
        int w0 = (int)w0f, h0 = (int)h0f, d0 = (int)d0f;
        float aw0 = (w0 >= 0 && w0 <= WWID - 1) ? (1.0f - tw) : 0.0f;
        float aw1 = (w0 + 1 >= 0 && w0 + 1 <= WWID - 1) ? tw : 0.0f;
        float ah0 = (h0 >= 0 && h0 <= HH - 1) ? (1.0f - th) : 0.0f;
        float ah1 = (h0 + 1 >= 0 && h0 + 1 <= HH - 1) ? th : 0.0f;
        float ad0 = (d0 >= 0 && d0 <= ZB - 1) ? (1.0f - td) : 0.0f;
        float ad1 = (d0 + 1 >= 0 && d0 + 1 <= ZB - 1) ? td : 0.0f;
        C.lv[ss] = ((ad0 + ad1) * (ah0 + ah1) * (aw0 + aw1) > 0.0f) ? 1 : 0;
        int h0c = min(max(h0, 0), HH - 1), h1c = min(max(h0 + 1, 0), HH - 1);
        int d0c = min(max(d0, 0), ZB - 1), d1c = min(max(d0 + 1, 0), ZB - 1);
        int wb = min(max(w0, 0), WWID - 2);
        float ws0 = (wb == w0) ? aw0 : ((wb == w0 + 1) ? aw1 : 0.0f);
        float ws1 = (wb == w0) ? aw1 : ((wb == w0 - 1) ? aw0 : 0.0f);
        int od0 = d0c * (HH * WWID * FD), od1 = d1c * (HH * WWID * FD);
        int oh0 = h0c * (WWID * FD), oh1 = h1c * (WWID * FD);
        int ow = wb * FD;
        C.off[ss][0] = od0 + oh0 + ow; C.off[ss][1] = od0 + oh1 + ow;
        C.off[ss][2] = od1 + oh0 + ow; C.off[ss][3] = od1 + oh1 + ow;
        C.wdh[ss][0] = ad0 * ah0; C.wdh[ss][1] = ad0 * ah1;
        C.wdh[ss][2] = ad1 * ah0; C.wdh[ss][3] = ad1 * ah1;
        C.ws[ss][0] = ws0; C.ws[ss][1] = ws1;
    }

    int sq = lane >> 2, cch = lane & 3, side = cch >> 1;

    half4 Af0 = *reinterpret_cast<const half4*>(W2f + lane * 4);
    half4 Af1 = *reinterpret_cast<const half4*>(W2f + (64 + lane) * 4);
    f32x4 b20 = *reinterpret_cast<const f32x4*>(b2f + lane * 4);
    f32x4 b21 = *reinterpret_cast<const f32x4*>(b2f + (64 + lane) * 4);
    f32x4 w30 = *reinterpret_cast<const f32x4*>(w3f + lane * 4);
    f32x4 w31 = *reinterpret_cast<const f32x4*>(w3f + (64 + lane) * 4);
    float b3v = b3[0];

    uint4 L0[4], L1[4]; float u0[4], u1[4]; int lv0, lv1;
    float at[8];

    // ---- rounds 0..3: samples 0..63 -> LDS rows 0..63 (2-slot pipeline) ----
    rissue<0>(gb, sq, cch, side, C, L0, u0, lv0);
    rissue<1>(gb, sq, cch, side, C, L1, u1, lv1);
    rconsume(FL, 0 * 16 + sq, cch, side, L0, u0, lv0);
    rissue<2>(gb, sq, cch, side, C, L0, u0, lv0);
    rconsume(FL, 1 * 16 + sq, cch, side, L1, u1, lv1);
    rissue<3>(gb, sq, cch, side, C, L1, u1, lv1);
    rconsume(FL, 2 * 16 + sq, cch, side, L0, u0, lv0);
    rissue<4>(gb, sq, cch, side, C, L0, u0, lv0);   // round-4 loads fly over pass A
    rconsume(FL, 3 * 16 + sq, cch, side, L1, u1, lv1);

    // ---- pass A: MFMA over rows 0..63 ----
    #pragma unroll
    for (int tt = 0; tt < 4; ++tt) {
        half4 bfrag = *reinterpret_cast<const half4*>(
            FL + (tt * 16 + (lane & 15)) * SF + (lane >> 4) * 4);
        f32x4 c0 = __builtin_amdgcn_mfma_f32_16x16x16f16(Af0, bfrag, b20, 0, 0, 0);
        f32x4 c1 = __builtin_amdgcn_mfma_f32_16x16x16f16(Af1, bfrag, b21, 0, 0, 0);
        float p = 0.0f;
        #pragma unroll
        for (int r = 0; r < 4; ++r) {
            p = fmaf(fmaxf(c0[r], 0.0f), w30[r], p);
            p = fmaf(fmaxf(c1[r], 0.0f), w31[r], p);
        }
        p += __shfl_xor(p, 16);
        p += __shfl_xor(p, 32);
        at[tt] = p;
    }

    // ---- rounds 4..7: samples 64..127 -> same LDS rows (same-wave WAR ordered) ----
    rissue<5>(gb, sq, cch, side, C, L1, u1, lv1);
    rconsume(FL, 0 * 16 + sq, cch, side, L0, u0, lv0);
    rissue<6>(gb, sq, cch, side, C, L0, u0, lv0);
    rconsume(FL, 1 * 16 + sq, cch, side, L1, u1, lv1);
    rissue<7>(gb, sq, cch, side, C, L1, u1, lv1);
    rconsume(FL, 2 * 16 + sq, cch, side, L0, u0, lv0);
    rconsume(FL, 3 * 16 + sq, cch, side, L1, u1, lv1);

    // ---- pass B: MFMA over rows 0..63 (samples 64..127) ----
    #pragma unroll
    for (int tt = 0; tt < 4; ++tt) {
        half4 bfrag = *reinterpret_cast<const half4*>(
            FL + (tt * 16 + (lane & 15)) * SF + (lane >> 4) * 4);
        f32x4 c0 = __builtin_amdgcn_mfma_f32_16x16x16f16(Af0, bfrag, b20, 0, 0, 0);
        f32x4 c1 = __builtin_amdgcn_mfma_f32_16x16x16f16(Af1, bfrag, b21, 0, 0, 0);
        float p = 0.0f;
        #pragma unroll
        for (int r = 0; r < 4; ++r) {
            p = fmaf(fmaxf(c0[r], 0.0f), w30[r], p);
            p = fmaf(fmaxf(c1[r], 0.0f), w31[r], p);
        }
        p += __shfl_xor(p, 16);
        p += __shfl_xor(p, 32);
        at[tt + 4] = p;
    }

    int g2 = lane >> 4;
    float aS0 = at[0];
    aS0 = (g2 == 1) ? at[1] : aS0;
    aS0 = (g2 == 2) ? at[2] : aS0;
    aS0 = (g2 == 3) ? at[3] : aS0;
    float aS1 = at[4];
    aS1 = (g2 == 1) ? at[5] : aS1;
    aS1 = (g2 == 2) ? at[6] : aS1;
    aS1 = (g2 == 3) ? at[7] : aS1;
    aS0 += b3v; aS1 += b3v;

    float alpha0 = 1.0f / (1.0f + __expf(-aS0));
    float alpha1 = 1.0f / (1.0f + __expf(-aS1));
    float oma0 = 1.0f - alpha0 + 1e-10f;
    float oma1 = 1.0f - alpha1 + 1e-10f;

    // inclusive product scan over first 64 samples
    float P = oma0;
    #pragma unroll
    for (int off = 1; off < 64; off <<= 1) {
        float u = __shfl_up(P, off);
        if (lane >= off) P *= u;
    }
    float T64 = __shfl(P, 63);      // product of samples 0..63
    // inclusive product scan over second 64 samples
    float Q = oma1;
    #pragma unroll
    for (int off = 1; off < 64; off <<= 1) {
        float u = __shfl_up(Q, off);
        if (lane >= off) Q *= u;
    }
    float e0 = __shfl_up(P, 1);
    if (lane == 0) e0 = 1.0f;
    float e1 = __shfl_up(Q, 1);
    e1 = (lane == 0) ? T64 : e1 * T64;

    float w0 = alpha0 * e0;
    float w1 = alpha1 * e1;
    w_out[(size_t)ray * SNUM + lane] = w0;
    w_out[(size_t)ray * SNUM + 64 + lane] = w1;

    float pv = w0 * t0 + w1 * t1;
    #pragma unroll
    for (int o = 32; o > 0; o >>= 1) pv += __shfl_xor(pv, o);
    if (lane == 0) pred_out[ray] = pv;
}

extern "C" void kernel_launch(void* const* d_in, const int* in_sizes, int n_in,
                              void* d_out, int out_size, void* d_ws, size_t ws_size,
                              hipStream_t stream) {
    const float* dec = (const float*)d_in[0];
    const float* ro  = (const float*)d_in[1];
    const float* rd  = (const float*)d_in[2];
    const float* lng = (const float*)d_in[3];
    const float* lnb = (const float*)d_in[4];
    const float* W1  = (const float*)d_in[5];
    const float* b1  = (const float*)d_in[6];
    const float* W2  = (const float*)d_in[7];
    const float* b2  = (const float*)d_in[8];
    const float* W3  = (const float*)d_in[9];
    const float* b3  = (const float*)d_in[10];

    float* out = (float*)d_out;
    char*  wsb = (char*)d_ws;
    _Float16* Af  = (_Float16*)wsb;                      // 2 MB
    _Float16* W1T = (_Float16*)(wsb + (2u << 20));       // 4 MB
    _Float16* gh  = (_Float16*)(wsb + (6u << 20));       // 16.8 MB
    _Float16* W2f = (_Float16*)(wsb + (23u << 20));              // 1 KB
    float*    b2f = (float*)(wsb + (23u << 20) + 4096);          // 2 KB
    float*    w3f = (float*)(wsb + (23u << 20) + 8192);          // 2 KB

    // dispatch 1: LN (blocks 0..2047) + W1 transpose (blocks 2048..2559)
    prep_kernel<<<NTOK + (ODIM / 64) * (DINP / 64), 256, 0, stream>>>(
        dec, lng, lnb, W2, b2, W3, W1, Af, W1T, W2f, b2f, w3f);

    // dispatch 2: GEMM
    dim3 gg(ODIM / 128, NTOK / 128);
    gemm_mfma_kernel<<<gg, 256, 0, stream>>>(Af, W1T, b1, gh);

    // dispatch 3: ray march (serial; merge with tp is dead — 2 strikes)
    ray_fused_kernel<<<BATCH * RAYS / 4, 256, 0, stream>>>(ro, rd, gh, W2f, b2f, w3f, b3,
                                                           out + OUT_PRED_OFF, out + OUT_W_OFF);

    // dispatch 4: nfg transpose
    tp_kernel<<<BATCH * ZB * HH, 256, 0, stream>>>(gh, out + OUT_NFG_OFF);
}

// Round 5
// 70.260 us; speedup vs baseline: 1.0766x; 1.0766x over previous
//
#include <hip/hip_runtime.h>
#include <math.h>

// ---- problem constants ----
#define DG   32
#define UF   4
#define ZB   16
#define FD   16
#define HH   128
#define WWID 128
#define SNUM 128
#define BATCH 2
#define RAYS  8192
#define NTOK  2048
#define DINP  512
#define ODIM  4096
#define MLPH  32

// d_out float offsets: (pred_depths, weights, nfg)
#define OUT_PRED_OFF 0
#define OUT_W_OFF    (BATCH*RAYS)
#define OUT_NFG_OFF  (OUT_W_OFF + BATCH*RAYS*SNUM)

typedef _Float16 half8 __attribute__((ext_vector_type(8)));
typedef _Float16 half4 __attribute__((ext_vector_type(4)));
typedef _Float16 h2 __attribute__((ext_vector_type(2)));
typedef float f32x4 __attribute__((ext_vector_type(4)));

#define GLDS16(gp, lp) \
    __builtin_amdgcn_global_load_lds((const __attribute__((address_space(1))) void*)(gp), \
                                     (__attribute__((address_space(3))) void*)(lp), 16, 0, 0)

// ---------------- merged prep: blocks [0,NTOK) = LayerNorm, [NTOK,NTOK+512) = W1 transpose ----------------
__global__ __launch_bounds__(256) void prep_kernel(const float* __restrict__ dec,
                                                   const float* __restrict__ lng,
                                                   const float* __restrict__ lnb,
                                                   const float* __restrict__ W2,
                                                   const float* __restrict__ b2,
                                                   const float* __restrict__ W3,
                                                   const float* __restrict__ W1,
                                                   _Float16* __restrict__ Af,
                                                   _Float16* __restrict__ W1T,
                                                   _Float16* __restrict__ W2f,
                                                   float* __restrict__ b2f,
                                                   float* __restrict__ w3f) {
    int tid = threadIdx.x;
    if (blockIdx.x < NTOK) {
        // ---- LayerNorm -> f16 A (block 0 also packs MLP frags) ----
        int t = blockIdx.x;
        const float2* row = reinterpret_cast<const float2*>(dec + (size_t)t * DINP);
        float2 v = row[tid];

        __shared__ float red[4];
        __shared__ float stat[2];

        float s = v.x + v.y;
        #pragma unroll
        for (int o = 32; o > 0; o >>= 1) s += __shfl_down(s, o);
        if ((tid & 63) == 0) red[tid >> 6] = s;
        __syncthreads();
        if (tid == 0) stat[0] = (red[0] + red[1] + red[2] + red[3]) * (1.0f / DINP);
        __syncthreads();
        float mu = stat[0];

        float dx = v.x - mu, dy = v.y - mu;
        float q = dx * dx + dy * dy;
        #pragma unroll
        for (int o = 32; o > 0; o >>= 1) q += __shfl_down(q, o);
        if ((tid & 63) == 0) red[tid >> 6] = q;
        __syncthreads();
        if (tid == 0) {
            float var = (red[0] + red[1] + red[2] + red[3]) * (1.0f / DINP);
            stat[1] = 1.0f / sqrtf(var + 1e-5f);
        }
        __syncthreads();
        float rstd = stat[1];

        int c = 2 * tid;
        h2 o2;
        o2.x = (_Float16)(dx * rstd * lng[c]     + lnb[c]);
        o2.y = (_Float16)(dy * rstd * lng[c + 1] + lnb[c + 1]);
        *reinterpret_cast<h2*>(Af + (size_t)t * DINP + c) = o2;

        // block 0: pack MLP weights into MFMA fragment order.
        if (blockIdx.x == 0 && tid < 128) {
            int jt = tid >> 6, l = tid & 63;
            int sub = l & 15, g = l >> 4;
            #pragma unroll
            for (int e = 0; e < 4; ++e) {
                W2f[(jt * 64 + l) * 4 + e] = (_Float16)W2[(g * 4 + e) * MLPH + jt * 16 + sub];
                b2f[(jt * 64 + l) * 4 + e] = b2[jt * 16 + g * 4 + e];
                w3f[(jt * 64 + l) * 4 + e] = W3[jt * 16 + g * 4 + e];
            }
        }
    } else {
        // ---- W1 (512x4096 f32) -> W1T (4096x512 f16) ----
        __shared__ float st[64][65];
        int blk = blockIdx.x - NTOK;          // [0, 512)
        int c0 = (blk & 63) * 64;
        int k0 = (blk >> 6) * 64;
        {
            int r = tid >> 2, cq = (tid & 3) * 16;
            const float* src = W1 + (size_t)(k0 + r) * ODIM + c0 + cq;
            #pragma unroll
            for (int qq = 0; qq < 4; ++qq) {
                float4 v = *reinterpret_cast<const float4*>(src + qq * 4);
                st[r][cq + qq * 4 + 0] = v.x;
                st[r][cq + qq * 4 + 1] = v.y;
                st[r][cq + qq * 4 + 2] = v.z;
                st[r][cq + qq * 4 + 3] = v.w;
            }
        }
        __syncthreads();
        {
            int cc = tid >> 2, kq = (tid & 3) * 16;
            _Float16 tmp[16];
            #pragma unroll
            for (int i = 0; i < 16; ++i) tmp[i] = (_Float16)st[kq + i][cc];
            _Float16* dst = W1T + (size_t)(c0 + cc) * DINP + k0 + kq;
            *reinterpret_cast<half8*>(dst)     = *reinterpret_cast<half8*>(&tmp[0]);
            *reinterpret_cast<half8*>(dst + 8) = *reinterpret_cast<half8*>(&tmp[8]);
        }
    }
}

// ---------------- MFMA GEMM -> grid_h (B,Z,H,W,F) f16 ----------------
__global__ __launch_bounds__(256, 2) void gemm_mfma_kernel(
        const _Float16* __restrict__ Af, const _Float16* __restrict__ W1T,
        const float* __restrict__ bias, _Float16* __restrict__ gh) {
    __shared__ _Float16 As[128 * 32];
    __shared__ _Float16 Bs[128 * 32];

    int tid = threadIdx.x;
    int l = tid & 63, w = tid >> 6;
    int wr = w >> 1, wc = w & 1;
    int row0 = blockIdx.y * 128;
    int col0 = blockIdx.x * 128;

    const char* Ag0 = (const char*)Af + (size_t)(row0 + w * 32 + (l >> 2)) * (DINP * 2) + (l & 3) * 16;
    const char* Ag1 = Ag0 + 16 * (DINP * 2);
    const char* Bg0 = (const char*)W1T + (size_t)(col0 + w * 32 + (l >> 2)) * (DINP * 2) + (l & 3) * 16;
    const char* Bg1 = Bg0 + 16 * (DINP * 2);
    char* lA0 = (char*)As + w * 2048;
    char* lA1 = lA0 + 1024;
    char* lB0 = (char*)Bs + w * 2048;
    char* lB1 = lB0 + 1024;

    f32x4 acc[4][4] = {};

    for (int kk = 0; kk < DINP; kk += 32) {
        GLDS16(Ag0, lA0); GLDS16(Ag1, lA1);
        GLDS16(Bg0, lB0); GLDS16(Bg1, lB1);
        Ag0 += 64; Ag1 += 64; Bg0 += 64; Bg1 += 64;
        __syncthreads();

        half8 af[4], bf[4];
        #pragma unroll
        for (int m = 0; m < 4; ++m)
            af[m] = *reinterpret_cast<const half8*>(As + (wr * 64 + m * 16 + (l & 15)) * 32 + (l >> 4) * 8);
        #pragma unroll
        for (int n = 0; n < 4; ++n)
            bf[n] = *reinterpret_cast<const half8*>(Bs + (wc * 64 + n * 16 + (l & 15)) * 32 + (l >> 4) * 8);
        #pragma unroll
        for (int m = 0; m < 4; ++m)
            #pragma unroll
            for (int n = 0; n < 4; ++n)
                acc[m][n] = __builtin_amdgcn_mfma_f32_16x16x32_f16(af[m], bf[n], acc[m][n], 0, 0, 0);
        __syncthreads();
    }

    #pragma unroll
    for (int n = 0; n < 4; ++n) {
        int c = col0 + wc * 64 + n * 16 + (l & 15);
        float bv = bias[c];
        int f = c & 15, z = (c >> 4) & 15, v = (c >> 8) & 3, u = (c >> 10) & 3;
        #pragma unroll
        for (int m = 0; m < 4; ++m) {
            int rbase = row0 + wr * 64 + m * 16 + ((l >> 4) << 2);
            #pragma unroll
            for (int j = 0; j < 4; ++j) {
                int t = rbase + j;
                int bb = t >> 10;
                int g = t & 1023;
                int i = g >> 5, j2 = g & 31;
                int h = i * 4 + u, wq = j2 * 4 + v;
                size_t gaddr = ((((size_t)(bb * ZB + z) * HH + h) * WWID + wq) << 4) + f;
                gh[gaddr] = (_Float16)(acc[m][n][j] + bv);
            }
        }
    }
}

// ---------------- transpose grid_h (B,Z,H,W,F) f16 -> nfg (B,F,Z,H,W) f32 ----------------
__global__ __launch_bounds__(256) void tp_kernel(const _Float16* __restrict__ gh,
                                                 float* __restrict__ nfg) {
    int blk = blockIdx.x;           // b*2048 + z*128 + h
    int bb = blk >> 11, z = (blk >> 7) & 15, h = blk & 127;
    __shared__ float sl[128 * 17];  // [w][f] padded
    int tid = threadIdx.x;
    const uint4* src = reinterpret_cast<const uint4*>(gh + (size_t)blk * 2048);
    uint4 v = src[tid];             // 8 f16; idx = tid*8
    int wv = tid >> 1, fb = (tid & 1) * 8;
    h2 p0 = __builtin_bit_cast(h2, v.x);
    h2 p1 = __builtin_bit_cast(h2, v.y);
    h2 p2 = __builtin_bit_cast(h2, v.z);
    h2 p3 = __builtin_bit_cast(h2, v.w);
    float* sr = &sl[wv * 17 + fb];
    sr[0] = (float)p0.x; sr[1] = (float)p0.y;
    sr[2] = (float)p1.x; sr[3] = (float)p1.y;
    sr[4] = (float)p2.x; sr[5] = (float)p2.y;
    sr[6] = (float)p3.x; sr[7] = (float)p3.y;
    __syncthreads();
    int f = tid >> 4, w0 = (tid & 15) * 8;
    float* dst = nfg + (((size_t)(bb * FD + f) * ZB + z) * (HH * WWID)) + h * WWID + w0;
    float4 o0, o1;
    o0.x = sl[(w0 + 0) * 17 + f]; o0.y = sl[(w0 + 1) * 17 + f];
    o0.z = sl[(w0 + 2) * 17 + f]; o0.w = sl[(w0 + 3) * 17 + f];
    o1.x = sl[(w0 + 4) * 17 + f]; o1.y = sl[(w0 + 5) * 17 + f];
    o1.z = sl[(w0 + 6) * 17 + f]; o1.w = sl[(w0 + 7) * 17 + f];
    *reinterpret_cast<float4*>(dst) = o0;
    *reinterpret_cast<float4*>(dst + 4) = o1;
}

// ---------------- gather helper: trilinear via 4x 64B pair-loads (w-corners contiguous) ----------------
// (round-2 proven version, bit-identical accumulation)
__device__ __forceinline__ void gather_feat(const _Float16* __restrict__ gb,
                                            float px, float py, float pz,
                                            h2* __restrict__ a) {
    float fw = (py * (1.0f / 51.2f) + 1.0f) * 63.5f;
    float fh = (px * (1.0f / 51.2f) + 1.0f) * 63.5f;
    float fd = (pz + 5.0f) * (0.25f * 7.5f);
    float w0f = floorf(fw), h0f = floorf(fh), d0f = floorf(fd);
    float tw = fw - w0f, th = fh - h0f, td = fd - d0f;
    int w0 = (int)w0f, h0 = (int)h0f, d0 = (int)d0f;

    float aw0 = (w0 >= 0 && w0 <= WWID - 1) ? (1.0f - tw) : 0.0f;
    float aw1 = (w0 + 1 >= 0 && w0 + 1 <= WWID - 1) ? tw : 0.0f;
    float ah0 = (h0 >= 0 && h0 <= HH - 1) ? (1.0f - th) : 0.0f;
    float ah1 = (h0 + 1 >= 0 && h0 + 1 <= HH - 1) ? th : 0.0f;
    float ad0 = (d0 >= 0 && d0 <= ZB - 1) ? (1.0f - td) : 0.0f;
    float ad1 = (d0 + 1 >= 0 && d0 + 1 <= ZB - 1) ? td : 0.0f;

    // all-corner-weights-zero -> output is exactly zero; skip every load.
    if ((ad0 + ad1) * (ah0 + ah1) * (aw0 + aw1) <= 0.0f) return;

    int h0c = min(max(h0, 0), HH - 1),   h1c = min(max(h0 + 1, 0), HH - 1);
    int d0c = min(max(d0, 0), ZB - 1),   d1c = min(max(d0 + 1, 0), ZB - 1);
    // w pair: both slots always valid memory; weights route aw0/aw1 to the right slot.
    int wb = min(max(w0, 0), WWID - 2);
    float ws0 = (wb == w0) ? aw0 : ((wb == w0 + 1) ? aw1 : 0.0f);
    float ws1 = (wb == w0) ? aw1 : ((wb == w0 - 1) ? aw0 : 0.0f);

    int od0 = d0c * (HH * WWID * FD), od1 = d1c * (HH * WWID * FD);
    int oh0 = h0c * (WWID * FD),      oh1 = h1c * (WWID * FD);
    int ow  = wb * FD;

#define CPAIR(OFF, WDH) do { \
        const uint4* cp_ = reinterpret_cast<const uint4*>(gb + (OFF)); \
        uint4 A_ = cp_[0], B_ = cp_[1], C_ = cp_[2], D_ = cp_[3]; \
        _Float16 u0_ = (_Float16)((WDH) * ws0); \
        _Float16 u1_ = (_Float16)((WDH) * ws1); \
        h2 W0_ = {u0_, u0_}; h2 W1_ = {u1_, u1_}; \
        a[0] += __builtin_bit_cast(h2, A_.x) * W0_; \
        a[1] += __builtin_bit_cast(h2, A_.y) * W0_; \
        a[2] += __builtin_bit_cast(h2, A_.z) * W0_; \
        a[3] += __builtin_bit_cast(h2, A_.w) * W0_; \
        a[4] += __builtin_bit_cast(h2, B_.x) * W0_; \
        a[5] += __builtin_bit_cast(h2, B_.y) * W0_; \
        a[6] += __builtin_bit_cast(h2, B_.z) * W0_; \
        a[7] += __builtin_bit_cast(h2, B_.w) * W0_; \
        a[0] += __builtin_bit_cast(h2, C_.x) * W1_; \
        a[1] += __builtin_bit_cast(h2, C_.y) * W1_; \
        a[2] += __builtin_bit_cast(h2, C_.z) * W1_; \
        a[3] += __builtin_bit_cast(h2, C_.w) * W1_; \
        a[4] += __builtin_bit_cast(h2, D_.x) * W1_; \
        a[5] += __builtin_bit_cast(h2, D_.y) * W1_; \
        a[6] += __builtin_bit_cast(h2, D_.z) * W1_; \
        a[7] += __builtin_bit_cast(h2, D_.w) * W1_; \
    } while (0)

    CPAIR(od0 + oh0 + ow, ad0 * ah0);
    CPAIR(od0 + oh1 + ow, ad0 * ah1);
    CPAIR(od1 + oh0 + ow, ad1 * ah0);
    CPAIR(od1 + oh1 + ow, ad1 * ah1);
#undef CPAIR
}

// ---------------- ray kernel v4: TWO WAVES PER RAY ----------------
// Each wave owns 64 samples (half=wvid&1); per-wave serial path halves vs v2
// (one gather, one stage, 4 MFMA rounds, one scan) and wave count doubles
// (16384 -> 32768) for latency hiding. Cross-half coupling (transmittance
// product + pred sum) is one LDS scalar exchange + one barrier, placed after
// both halves finish all heavy work. Weight math kept in the v2 op order
// (bit-identical w_out); pred_depths sum regrouped (2x64 + add) - f32 noise.
#define SF 24   // feat LDS stride (halves)
__global__ __launch_bounds__(256) void ray_fused_kernel(
        const float* __restrict__ orig, const float* __restrict__ dirs,
        const _Float16* __restrict__ gh,
        const _Float16* __restrict__ W2f, const float* __restrict__ b2f,
        const float* __restrict__ w3f, const float* __restrict__ b3,
        float* __restrict__ pred_out, float* __restrict__ w_out) {
    int tid = threadIdx.x;
    int lane = tid & 63, wvid = tid >> 6;
    int rloc = wvid >> 1, half = wvid & 1;
    int ray = blockIdx.x * 2 + rloc;
    int bb = ray >> 13;

    __shared__ _Float16 featLDS[4 * 64 * SF];   // 12KB, 3KB per wave
    __shared__ float xch[4];                    // [rloc*2 + {T64, pv0}]
    _Float16* FL = &featLDS[wvid * 64 * SF];

    const float* o3 = orig + (size_t)ray * 3;
    const float* d3 = dirs + (size_t)ray * 3;
    float ox = o3[0], oy = o3[1], oz = o3[2];
    float dx = d3[0], dy = d3[1], dz = d3[2];
    const _Float16* gb = gh + (size_t)bb * (ZB * HH * WWID * FD);

    int s = half * 64 + lane;
    float t = 1.0f + 49.0f * ((float)s * (1.0f / 127.0f));

    h2 acc[8] = {};
    gather_feat(gb, ox + dx * t, oy + dy * t, oz + dz * t, acc);

    // stage this wave's 64 samples into its private LDS slice
    {
        uint4 p0, p1;
        p0.x = __builtin_bit_cast(unsigned int, acc[0]);
        p0.y = __builtin_bit_cast(unsigned int, acc[1]);
        p0.z = __builtin_bit_cast(unsigned int, acc[2]);
        p0.w = __builtin_bit_cast(unsigned int, acc[3]);
        p1.x = __builtin_bit_cast(unsigned int, acc[4]);
        p1.y = __builtin_bit_cast(unsigned int, acc[5]);
        p1.z = __builtin_bit_cast(unsigned int, acc[6]);
        p1.w = __builtin_bit_cast(unsigned int, acc[7]);
        *reinterpret_cast<uint4*>(FL + lane * SF)     = p0;
        *reinterpret_cast<uint4*>(FL + lane * SF + 8) = p1;
    }
    // same-wave ds_write -> ds_read: compiler inserts lgkmcnt wait; no barrier needed

    half4 Af0 = *reinterpret_cast<const half4*>(W2f + lane * 4);
    half4 Af1 = *reinterpret_cast<const half4*>(W2f + (64 + lane) * 4);
    f32x4 b20 = *reinterpret_cast<const f32x4*>(b2f + lane * 4);
    f32x4 b21 = *reinterpret_cast<const f32x4*>(b2f + (64 + lane) * 4);
    f32x4 w30 = *reinterpret_cast<const f32x4*>(w3f + lane * 4);
    f32x4 w31 = *reinterpret_cast<const f32x4*>(w3f + (64 + lane) * 4);
    float b3v = b3[0];

    float at[4];
    #pragma unroll
    for (int tt = 0; tt < 4; ++tt) {
        half4 bfrag = *reinterpret_cast<const half4*>(
            FL + (tt * 16 + (lane & 15)) * SF + (lane >> 4) * 4);
        f32x4 c0 = __builtin_amdgcn_mfma_f32_16x16x16f16(Af0, bfrag, b20, 0, 0, 0);
        f32x4 c1 = __builtin_amdgcn_mfma_f32_16x16x16f16(Af1, bfrag, b21, 0, 0, 0);
        float p = 0.0f;
        #pragma unroll
        for (int r = 0; r < 4; ++r) {
            p = fmaf(fmaxf(c0[r], 0.0f), w30[r], p);
            p = fmaf(fmaxf(c1[r], 0.0f), w31[r], p);
        }
        p += __shfl_xor(p, 16);
        p += __shfl_xor(p, 32);
        at[tt] = p;
    }
    int g2 = lane >> 4;
    float aS = at[0];
    aS = (g2 == 1) ? at[1] : aS;
    aS = (g2 == 2) ? at[2] : aS;
    aS = (g2 == 3) ? at[3] : aS;
    aS += b3v;

    float alpha = 1.0f / (1.0f + __expf(-aS));
    float oma = 1.0f - alpha + 1e-10f;

    // inclusive product scan over this wave's 64 samples
    float P = oma;
    #pragma unroll
    for (int off = 1; off < 64; off <<= 1) {
        float u = __shfl_up(P, off);
        if (lane >= off) P *= u;
    }
    float T = __shfl(P, 63);            // product of this half's samples
    float e = __shfl_up(P, 1);
    if (lane == 0) e = 1.0f;            // exclusive scan

    if (half == 0) {
        float wv = alpha * e;           // identical op order to v2
        w_out[(size_t)ray * SNUM + lane] = wv;
        float pv = wv * t;
        #pragma unroll
        for (int o = 32; o > 0; o >>= 1) pv += __shfl_xor(pv, o);
        if (lane == 0) { xch[rloc * 2] = T; xch[rloc * 2 + 1] = pv; }
    }
    __syncthreads();
    if (half == 1) {
        float T0 = xch[rloc * 2];
        float es = (lane == 0) ? T0 : e * T0;   // identical op order to v2
        float wv = alpha * es;
        w_out[(size_t)ray * SNUM + 64 + lane] = wv;
        float pv = wv * t;
        #pragma unroll
        for (int o = 32; o > 0; o >>= 1) pv += __shfl_xor(pv, o);
        if (lane == 0) pred_out[ray] = pv + xch[rloc * 2 + 1];
    }
}

extern "C" void kernel_launch(void* const* d_in, const int* in_sizes, int n_in,
                              void* d_out, int out_size, void* d_ws, size_t ws_size,
                              hipStream_t stream) {
    const float* dec = (const float*)d_in[0];
    const float* ro  = (const float*)d_in[1];
    const float* rd  = (const float*)d_in[2];
    const float* lng = (const float*)d_in[3];
    const float* lnb = (const float*)d_in[4];
    const float* W1  = (const float*)d_in[5];
    const float* b1  = (const float*)d_in[6];
    const float* W2  = (const float*)d_in[7];
    const float* b2  = (const float*)d_in[8];
    const float* W3  = (const float*)d_in[9];
    const float* b3  = (const float*)d_in[10];

    float* out = (float*)d_out;
    char*  wsb = (char*)d_ws;
    _Float16* Af  = (_Float16*)wsb;                      // 2 MB
    _Float16* W1T = (_Float16*)(wsb + (2u << 20));       // 4 MB
    _Float16* gh  = (_Float16*)(wsb + (6u << 20));       // 16.8 MB
    _Float16* W2f = (_Float16*)(wsb + (23u << 20));              // 1 KB
    float*    b2f = (float*)(wsb + (23u << 20) + 4096);          // 2 KB
    float*    w3f = (float*)(wsb + (23u << 20) + 8192);          // 2 KB

    // dispatch 1: LN (blocks 0..2047) + W1 transpose (blocks 2048..2559)
    prep_kernel<<<NTOK + (ODIM / 64) * (DINP / 64), 256, 0, stream>>>(
        dec, lng, lnb, W2, b2, W3, W1, Af, W1T, W2f, b2f, w3f);

    // dispatch 2: GEMM
    dim3 gg(ODIM / 128, NTOK / 128);
    gemm_mfma_kernel<<<gg, 256, 0, stream>>>(Af, W1T, b1, gh);

    // dispatch 3: ray march, 2 waves per ray (2 rays per 256-thread block)
    ray_fused_kernel<<<BATCH * RAYS / 2, 256, 0, stream>>>(ro, rd, gh, W2f, b2f, w3f, b3,
                                                           out + OUT_PRED_OFF, out + OUT_W_OFF);

    // dispatch 4: nfg transpose
    tp_kernel<<<BATCH * ZB * HH, 256, 0, stream>>>(gh, out + OUT_NFG_OFF);
}